// Round 3
// baseline (2666.502 us; speedup 1.0000x reference)
//
#include <hip/hip_runtime.h>

#define CRF_B 512
#define CRF_T 2048
#define CRF_K 32
#define CRF_Q (CRF_T / 4)   // 512 packed-bp dwords per batch per column

__global__ __launch_bounds__(64, 1) void crf_fused(
    const float* __restrict__ pot,    // [B,T,K]
    const float* __restrict__ trans,  // [K,K]
    float* __restrict__ out,          // [B,T,K] one-hot fp32
    unsigned int* __restrict__ bp)    // ws: [B, Q, K] packed backpointers
{
    const int b = blockIdx.x;
    const int l = threadIdx.x;
    const int j = l & 31;             // upper half duplicates lower (benign)

    // lane j's column of transitions: tr[i] = trans[i][j]
    float tr[CRF_K];
#pragma unroll
    for (int i = 0; i < CRF_K; ++i) tr[i] = trans[i * CRF_K + j];

    const float* potb = pot + (size_t)b * (CRF_T * CRF_K);
    unsigned int* bpb = bp + (size_t)b * (CRF_Q * CRF_K);
    float* outb = out + (size_t)b * (CRF_T * CRF_K);

    // state vector lives in LDS; broadcast-read each step (8x ds_read_b128,
    // all lanes same address -> conflict-free broadcast; single wave -> DS
    // in-order, no barrier needed)
    __shared__ alignas(16) float st[CRF_K];

    float vstate = potb[j];           // t = 0
    st[j] = vstate;                   // both halves write same value (benign)

    // potential double-buffer: cur = this group's pot rows, nxt = next group's
    float cur[4], nxt[4];
#pragma unroll
    for (int t = 1; t < 4; ++t) cur[t] = potb[t * CRF_K + j];

    const float4* stv = (const float4*)st;

    for (int q = 0; q < CRF_Q; ++q) {
        // prefetch next group's potentials (issued early, consumed next q)
        {
            const int tb = (q + 1) * 4;
#pragma unroll
            for (int sx = 0; sx < 4; ++sx) {
                int t = tb + sx; if (t > CRF_T - 1) t = CRF_T - 1;
                nxt[sx] = potb[t * CRF_K + j];
            }
        }
        unsigned int bpack = 0;
#pragma unroll
        for (int sx = 0; sx < 4; ++sx) {
            if (q == 0 && sx == 0) continue;   // t=0 has no backpointer
            // broadcast-read full state vector
            float sv[CRF_K];
#pragma unroll
            for (int k = 0; k < 8; ++k) {
                float4 a = stv[k];
                sv[4 * k + 0] = a.x; sv[4 * k + 1] = a.y;
                sv[4 * k + 2] = a.z; sv[4 * k + 3] = a.w;
            }
            // candidates
            float c[CRF_K];
#pragma unroll
            for (int i = 0; i < CRF_K; ++i) c[i] = sv[i] + tr[i];
            // tournament: value chain via v_max (short dep chain), index via
            // cmp+cndmask; right wins only if strictly greater -> first-index
            float v16[16]; int x16[16];
#pragma unroll
            for (int k = 0; k < 16; ++k) {
                bool t = c[2 * k + 1] > c[2 * k];
                v16[k] = fmaxf(c[2 * k], c[2 * k + 1]);
                x16[k] = t ? (2 * k + 1) : (2 * k);
            }
            float v8[8]; int x8[8];
#pragma unroll
            for (int k = 0; k < 8; ++k) {
                bool t = v16[2 * k + 1] > v16[2 * k];
                v8[k] = fmaxf(v16[2 * k], v16[2 * k + 1]);
                x8[k] = t ? x16[2 * k + 1] : x16[2 * k];
            }
            float v4[4]; int x4[4];
#pragma unroll
            for (int k = 0; k < 4; ++k) {
                bool t = v8[2 * k + 1] > v8[2 * k];
                v4[k] = fmaxf(v8[2 * k], v8[2 * k + 1]);
                x4[k] = t ? x8[2 * k + 1] : x8[2 * k];
            }
            float v2[2]; int x2[2];
#pragma unroll
            for (int k = 0; k < 2; ++k) {
                bool t = v4[2 * k + 1] > v4[2 * k];
                v2[k] = fmaxf(v4[2 * k], v4[2 * k + 1]);
                x2[k] = t ? x4[2 * k + 1] : x4[2 * k];
            }
            bool tf = v2[1] > v2[0];
            float m = fmaxf(v2[0], v2[1]);
            int  mi = tf ? x2[1] : x2[0];

            vstate = m + cur[sx];
            bpack |= ((unsigned int)mi) << (8 * sx);
            st[j] = vstate;            // feeds next step's broadcast read
        }
        bpb[q * CRF_K + j] = bpack;    // halves store identical values (benign)
#pragma unroll
        for (int sx = 0; sx < 4; ++sx) cur[sx] = nxt[sx];
    }

    // ---------------- last tag (argmax over final state, first-index ties) ----
    // st[] holds the final state vector
    int bt = 0; float bv = st[0];
#pragma unroll
    for (int jj = 1; jj < CRF_K; ++jj) {
        float v = st[jj];
        if (v > bv) { bv = v; bt = jj; }
    }
    int stag = __builtin_amdgcn_readfirstlane(bt);

    const int c = l & 31;
    // one-hot row for t = T-1 (halves write identical 128B row)
    outb[(CRF_T - 1) * CRF_K + c] = (c == stag) ? 1.0f : 0.0f;

    __threadfence();   // make own bp stores visible before read-back

    // ---------------- backtrack: lane c holds COLUMN c of bp ----------------
    for (int q0 = CRF_Q - 16; q0 >= 0; q0 -= 16) {
        unsigned int col[16];
#pragma unroll
        for (int r = 0; r < 16; ++r) col[r] = bpb[(q0 + r) * CRF_K + c];
#pragma unroll
        for (int r = 15; r >= 0; --r) {
#pragma unroll
            for (int bi = 3; bi >= 0; --bi) {
                const int t = (q0 + r) * 4 + bi;
                if (t == 0) continue;   // only q0==0, r==0, bi==0
                unsigned int dw = (unsigned int)__builtin_amdgcn_readlane((int)col[r], stag);
                stag = (int)((dw >> (8 * bi)) & 255u);
                outb[(size_t)(t - 1) * CRF_K + c] = (c == stag) ? 1.0f : 0.0f;
            }
        }
    }
}

extern "C" void kernel_launch(void* const* d_in, const int* in_sizes, int n_in,
                              void* d_out, int out_size, void* d_ws, size_t ws_size,
                              hipStream_t stream) {
    const float* pot   = (const float*)d_in[0];   // inputs [512,2048,32] fp32
    const float* trans = (const float*)d_in[1];   // transitions [32,32] fp32
    float* out = (float*)d_out;
    unsigned int* bp = (unsigned int*)d_ws;       // needs 33,554,432 B

    crf_fused<<<dim3(CRF_B), dim3(64), 0, stream>>>(pot, trans, out, bp);
}

// Round 5
// 2611.265 us; speedup vs baseline: 1.0212x; 1.0212x over previous
//
#include <hip/hip_runtime.h>

#define CRF_B 512
#define CRF_T 2048
#define CRF_K 32
#define CRF_Q (CRF_T / 4)   // 512 packed-bp dwords per batch per column

// Batch-fill bs[i] = state[i] via 32 independent ds_swizzle broadcasts
// (BitMode, or_mask = I): every lane of each 32-lane group reads group-lane I.
// Template recursion because the swizzle pattern must be an AST-level constant.
template<int I>
__device__ __forceinline__ void bcast(int v, float (&bs)[CRF_K]) {
    if constexpr (I < CRF_K) {
        bs[I] = __int_as_float(__builtin_amdgcn_ds_swizzle(v, (I << 5)));
        bcast<I + 1>(v, bs);
    }
}

__global__ __launch_bounds__(64, 1) void crf_fused(
    const float* __restrict__ pot,    // [B,T,K]
    const float* __restrict__ trans,  // [K,K]
    float* __restrict__ out,          // [B,T,K] one-hot fp32
    unsigned int* __restrict__ bp)    // ws: [B, Q, K] packed backpointers
{
    const int b = blockIdx.x;
    const int l = threadIdx.x;
    const int j = l & 31;             // upper half duplicates lower (benign)

    // lane j's column of transitions: tr[i] = trans[i][j]
    float tr[CRF_K];
#pragma unroll
    for (int i = 0; i < CRF_K; ++i) tr[i] = trans[i * CRF_K + j];

    const float* potb = pot + (size_t)b * (CRF_T * CRF_K);
    unsigned int* bpb = bp + (size_t)b * (CRF_Q * CRF_K);
    float* outb = out + (size_t)b * (CRF_T * CRF_K);

    float vstate = potb[j];           // t = 0

    // potential double-buffer: cur = this group's pot rows, nxt = next group's
    float cur[4], nxt[4];
#pragma unroll
    for (int t = 1; t < 4; ++t) cur[t] = potb[t * CRF_K + j];

    for (int q = 0; q < CRF_Q; ++q) {
        // prefetch next group's potentials (issued early, consumed next q)
        {
            const int tb = (q + 1) * 4;
#pragma unroll
            for (int sx = 0; sx < 4; ++sx) {
                int t = tb + sx; if (t > CRF_T - 1) t = CRF_T - 1;
                nxt[sx] = potb[t * CRF_K + j];
            }
        }
        unsigned int bpack = 0;
#pragma unroll
        for (int sx = 0; sx < 4; ++sx) {
            if (q == 0 && sx == 0) continue;   // t=0 has no backpointer

            // ---- broadcast phase: 32 independent ds_swizzle, batched ----
            float bs[CRF_K];
            bcast<0>(__float_as_int(vstate), bs);

            // ---- candidates ----
            float c[CRF_K];
#pragma unroll
            for (int i = 0; i < CRF_K; ++i) c[i] = bs[i] + tr[i];

            // ---- tournament: value via v_max (short chain), index via
            // cmp+cndmask; right wins only if strictly greater -> first-index
            float v16[16]; int x16[16];
#pragma unroll
            for (int k = 0; k < 16; ++k) {
                bool t = c[2 * k + 1] > c[2 * k];
                v16[k] = fmaxf(c[2 * k], c[2 * k + 1]);
                x16[k] = t ? (2 * k + 1) : (2 * k);
            }
            float v8[8]; int x8[8];
#pragma unroll
            for (int k = 0; k < 8; ++k) {
                bool t = v16[2 * k + 1] > v16[2 * k];
                v8[k] = fmaxf(v16[2 * k], v16[2 * k + 1]);
                x8[k] = t ? x16[2 * k + 1] : x16[2 * k];
            }
            float v4[4]; int x4[4];
#pragma unroll
            for (int k = 0; k < 4; ++k) {
                bool t = v8[2 * k + 1] > v8[2 * k];
                v4[k] = fmaxf(v8[2 * k], v8[2 * k + 1]);
                x4[k] = t ? x8[2 * k + 1] : x8[2 * k];
            }
            float v2[2]; int x2[2];
#pragma unroll
            for (int k = 0; k < 2; ++k) {
                bool t = v4[2 * k + 1] > v4[2 * k];
                v2[k] = fmaxf(v4[2 * k], v4[2 * k + 1]);
                x2[k] = t ? x4[2 * k + 1] : x4[2 * k];
            }
            bool tf = v2[1] > v2[0];
            float m = fmaxf(v2[0], v2[1]);
            int  mi = tf ? x2[1] : x2[0];

            vstate = m + cur[sx];
            bpack |= ((unsigned int)mi) << (8 * sx);
        }
        bpb[q * CRF_K + j] = bpack;    // halves store identical values (benign)
#pragma unroll
        for (int sx = 0; sx < 4; ++sx) cur[sx] = nxt[sx];
    }

    // ---------------- last tag (argmax over final state, first-index ties) ----
    __shared__ float fs[CRF_K];
    if (l < CRF_K) fs[l] = vstate;    // lanes 0-31 hold state[j] at lane j
    __syncthreads();
    int bt = 0; float bv = fs[0];
#pragma unroll
    for (int jj = 1; jj < CRF_K; ++jj) {
        float v = fs[jj];
        if (v > bv) { bv = v; bt = jj; }
    }
    int stag = __builtin_amdgcn_readfirstlane(bt);

    const int c = l & 31;
    // one-hot row for t = T-1 (halves write identical 128B row)
    outb[(CRF_T - 1) * CRF_K + c] = (c == stag) ? 1.0f : 0.0f;

    __threadfence();   // make own bp stores visible before read-back

    // ---------------- backtrack: lane c holds COLUMN c of bp ----------------
    for (int q0 = CRF_Q - 16; q0 >= 0; q0 -= 16) {
        unsigned int col[16];
#pragma unroll
        for (int r = 0; r < 16; ++r) col[r] = bpb[(q0 + r) * CRF_K + c];
#pragma unroll
        for (int r = 15; r >= 0; --r) {
#pragma unroll
            for (int bi = 3; bi >= 0; --bi) {
                const int t = (q0 + r) * 4 + bi;
                if (t == 0) continue;   // only q0==0, r==0, bi==0
                unsigned int dw = (unsigned int)__builtin_amdgcn_readlane((int)col[r], stag);
                stag = (int)((dw >> (8 * bi)) & 255u);
                outb[(size_t)(t - 1) * CRF_K + c] = (c == stag) ? 1.0f : 0.0f;
            }
        }
    }
}

extern "C" void kernel_launch(void* const* d_in, const int* in_sizes, int n_in,
                              void* d_out, int out_size, void* d_ws, size_t ws_size,
                              hipStream_t stream) {
    const float* pot   = (const float*)d_in[0];   // inputs [512,2048,32] fp32
    const float* trans = (const float*)d_in[1];   // transitions [32,32] fp32
    float* out = (float*)d_out;
    unsigned int* bp = (unsigned int*)d_ws;       // needs 33,554,432 B

    crf_fused<<<dim3(CRF_B), dim3(64), 0, stream>>>(pot, trans, out, bp);
}

// Round 6
// 2534.406 us; speedup vs baseline: 1.0521x; 1.0303x over previous
//
#include <hip/hip_runtime.h>

#define CRF_B 512
#define CRF_T 2048
#define CRF_K 32
#define CRF_Q (CRF_T / 4)   // 512 packed-bp dwords per batch per column

__global__ __launch_bounds__(64, 1) void crf_fused(
    const float* __restrict__ pot,    // [B,T,K]
    const float* __restrict__ trans,  // [K,K]
    float* __restrict__ out,          // [B,T,K] one-hot fp32
    unsigned int* __restrict__ bp)    // ws: [B, Q, K] packed backpointers
{
    const int b = blockIdx.x;
    const int l = threadIdx.x;
    const int j = l & 31;             // upper half duplicates lower (benign)

    // lane j's column of transitions: tr[i] = trans[i][j]
    float tr[CRF_K];
#pragma unroll
    for (int i = 0; i < CRF_K; ++i) tr[i] = trans[i * CRF_K + j];

    // hoisted odd constants for tournament level-1 index cndmask (VGPRs,
    // loop-invariant -- avoids 16 v_mov rematerializations per step)
    int oddc[16];
#pragma unroll
    for (int k = 0; k < 16; ++k) oddc[k] = 2 * k + 1;

    const float* potb = pot + (size_t)b * (CRF_T * CRF_K);
    unsigned int* bpb = bp + (size_t)b * (CRF_Q * CRF_K);
    float* outb = out + (size_t)b * (CRF_T * CRF_K);

    float vstate = potb[j];           // t = 0

    // potential double-buffer: cur = this group's pot rows, nxt = next group's
    float cur[4], nxt[4];
#pragma unroll
    for (int t = 1; t < 4; ++t) cur[t] = potb[t * CRF_K + j];

    for (int q = 0; q < CRF_Q; ++q) {
        // prefetch next group's potentials (issued early, consumed next q)
        {
            const int tb = (q + 1) * 4;
#pragma unroll
            for (int sx = 0; sx < 4; ++sx) {
                int t = tb + sx; if (t > CRF_T - 1) t = CRF_T - 1;
                nxt[sx] = potb[t * CRF_K + j];
            }
        }
        unsigned int bpack = 0;
#pragma unroll
        for (int sx = 0; sx < 4; ++sx) {
            if (q == 0 && sx == 0) continue;   // t=0 has no backpointer

            // ---- phase 1: transpose j-lanes -> wave-uniform SGPRs ----
            // all 32 readlanes batched; consumers pushed past the barrier so
            // the SGPR-write -> VALU-read hazard is amortized across the batch
            float s[CRF_K];
            const int vb = __float_as_int(vstate);
#pragma unroll
            for (int i = 0; i < CRF_K; ++i)
                s[i] = __int_as_float(__builtin_amdgcn_readlane(vb, i));
            __builtin_amdgcn_sched_barrier(0x14);  // only SALU+VMEM may cross

            // ---- phase 2: candidates ----
            float c[CRF_K];
#pragma unroll
            for (int i = 0; i < CRF_K; ++i) c[i] = s[i] + tr[i];
            __builtin_amdgcn_sched_barrier(0x14);

            // ---- phase 3: tournament (exact R2 semantics: value via v_max,
            // index via cmp+cndmask; right wins only if strictly greater ->
            // first-index argmax) ----
            float v16[16]; int x16[16];
#pragma unroll
            for (int k = 0; k < 16; ++k) {
                bool t = c[2 * k + 1] > c[2 * k];
                v16[k] = fmaxf(c[2 * k], c[2 * k + 1]);
                x16[k] = t ? oddc[k] : (2 * k);
            }
            float v8[8]; int x8[8];
#pragma unroll
            for (int k = 0; k < 8; ++k) {
                bool t = v16[2 * k + 1] > v16[2 * k];
                v8[k] = fmaxf(v16[2 * k], v16[2 * k + 1]);
                x8[k] = t ? x16[2 * k + 1] : x16[2 * k];
            }
            float v4[4]; int x4[4];
#pragma unroll
            for (int k = 0; k < 4; ++k) {
                bool t = v8[2 * k + 1] > v8[2 * k];
                v4[k] = fmaxf(v8[2 * k], v8[2 * k + 1]);
                x4[k] = t ? x8[2 * k + 1] : x8[2 * k];
            }
            float v2[2]; int x2[2];
#pragma unroll
            for (int k = 0; k < 2; ++k) {
                bool t = v4[2 * k + 1] > v4[2 * k];
                v2[k] = fmaxf(v4[2 * k], v4[2 * k + 1]);
                x2[k] = t ? x4[2 * k + 1] : x4[2 * k];
            }
            bool tf = v2[1] > v2[0];
            float m = fmaxf(v2[0], v2[1]);
            int  mi = tf ? x2[1] : x2[0];

            vstate = m + cur[sx];
            bpack |= ((unsigned int)mi) << (8 * sx);
        }
        bpb[q * CRF_K + j] = bpack;    // halves store identical values (benign)
#pragma unroll
        for (int sx = 0; sx < 4; ++sx) cur[sx] = nxt[sx];
    }

    // ---------------- last tag (argmax over final state, first-index ties) ----
    __shared__ float fs[CRF_K];
    if (l < CRF_K) fs[l] = vstate;    // lanes 0-31 hold state[j] at lane j
    __syncthreads();
    int bt = 0; float bv = fs[0];
#pragma unroll
    for (int jj = 1; jj < CRF_K; ++jj) {
        float v = fs[jj];
        if (v > bv) { bv = v; bt = jj; }
    }
    int stag = __builtin_amdgcn_readfirstlane(bt);

    const int c = l & 31;
    // one-hot row for t = T-1 (halves write identical 128B row)
    outb[(CRF_T - 1) * CRF_K + c] = (c == stag) ? 1.0f : 0.0f;

    __threadfence();   // make own bp stores visible before read-back

    // ---------------- backtrack: lane c holds COLUMN c of bp ----------------
    for (int q0 = CRF_Q - 16; q0 >= 0; q0 -= 16) {
        unsigned int col[16];
#pragma unroll
        for (int r = 0; r < 16; ++r) col[r] = bpb[(q0 + r) * CRF_K + c];
#pragma unroll
        for (int r = 15; r >= 0; --r) {
#pragma unroll
            for (int bi = 3; bi >= 0; --bi) {
                const int t = (q0 + r) * 4 + bi;
                if (t == 0) continue;   // only q0==0, r==0, bi==0
                unsigned int dw = (unsigned int)__builtin_amdgcn_readlane((int)col[r], stag);
                stag = (int)((dw >> (8 * bi)) & 255u);
                outb[(size_t)(t - 1) * CRF_K + c] = (c == stag) ? 1.0f : 0.0f;
            }
        }
    }
}

extern "C" void kernel_launch(void* const* d_in, const int* in_sizes, int n_in,
                              void* d_out, int out_size, void* d_ws, size_t ws_size,
                              hipStream_t stream) {
    const float* pot   = (const float*)d_in[0];   // inputs [512,2048,32] fp32
    const float* trans = (const float*)d_in[1];   // transitions [32,32] fp32
    float* out = (float*)d_out;
    unsigned int* bp = (unsigned int*)d_ws;       // needs 33,554,432 B

    crf_fused<<<dim3(CRF_B), dim3(64), 0, stream>>>(pot, trans, out, bp);
}